// Round 11
// baseline (28.842 us; speedup 1.0000x reference)
//
#include <hip/hip_runtime.h>

// Sobel3D: data [4,1,256,256,64] f32 -> out [4,1,256,256,64] f32 (0/1).
// out = 1 iff >=2 of the 3 directional Sobel gradients are nonzero.
//
// Separable decomposition (cross-correlation, SAME zero padding):
//   per (d,h) row:  S[i] = x[i-1]+2x[i]+x[i+1],  D[i] = x[i-1]-x[i+1]
//   per plane d:    ds = D(h-1)+D(h)+D(h+1), ss = S(h-1)+S(h)+S(h+1),
//                   sd = S(h-1)-S(h+1)
//   Gx = ds(d-1)+2*ds(d)+ds(d+1); Gy = ss(d-1)-ss(d+1); Gz = sd(d-1)+sd(d)+sd(d+1)
//
// R11 = R10 (28.8us) with the XCD slab panel-blocked for L2 capacity:
// each XCD's 1024-block slab is decoded in panels of 4 h-tiles x 64 d-chunks
// (256 blocks). Panel working set ~= 34 rows x 256 planes x 256B ~= 2.2MB
// < 4MiB per-XCD L2 (R10's effective span was ~8 h-tiles ~= 5-6.5MB, spilling
// h-halo re-reads to L3). All else identical to R10.
// Invariants (R6-R9): VGPR <= 64 (8 waves/SIMD), DC=4 all-6-planes-upfront
// register pipeline, 8192 fine blocks, plain stores, no LDS/barriers.

constexpr int DDIM = 256;
constexpr int HDIM = 256;
constexpr int WWID = 64;
constexpr int DC   = 4;    // output d-planes per block
constexpr int HT   = 8;    // h rows per block (2 waves)

struct P3 { float ds[4], ss[4], sd[4]; };

__device__ __forceinline__ float dpp_up1(float v) {   // lane n <- lane n-1 (16-lane row), edge->0
  return __builtin_bit_cast(float, __builtin_amdgcn_update_dpp(
      0, __builtin_bit_cast(int, v), 0x111, 0xf, 0xf, true));  // row_shr:1
}
__device__ __forceinline__ float dpp_dn1(float v) {   // lane n <- lane n+1 (16-lane row), edge->0
  return __builtin_bit_cast(float, __builtin_amdgcn_update_dpp(
      0, __builtin_bit_cast(int, v), 0x101, 0xf, 0xf, true));  // row_shl:1
}

__global__ __launch_bounds__(128) void sobel3d_kernel(
    const float* __restrict__ in, float* __restrict__ out) {
  // ---- XCD-aware swizzle, panel-blocked (bijective: 8192 % 8 == 0) ----
  // XCD x owns swz in [x*1024, (x+1)*1024): batch b = x/2, h-tile half
  // 16*(x&1).. +15. Within the slab: 4 panels of (4 h-tiles x 64 d-chunks).
  const int bid  = blockIdx.x;                   // 0..8191
  const int swz  = (bid & 7) * 1024 + (bid >> 3);
  const int b    = swz >> 11;                    // /2048: batch
  const int rem  = swz & 2047;                   // 0..2047 within batch-half pair
  const int half = rem >> 10;                    // 0/1: which 16-h-tile half
  const int prem = rem & 1023;                   // within slab
  const int pan  = prem >> 8;                    // 0..3: panel (4 h-tiles each)
  const int pin  = prem & 255;                   // within panel
  const int hx   = half * 16 + pan * 4 + (pin >> 6);   // 0..31: h-tile
  const int dx   = pin & 63;                     // 0..63: d-chunk (fastest)

  const int lane = threadIdx.x;          // 0..63
  const int wg   = lane & 15;            // w-group within row (16 x float4 = row)
  const int hs   = lane >> 4;            // h-sub within wave
  const int w0   = wg * 4;
  const int h    = hx * HT + threadIdx.y * 4 + hs;
  const int d0   = dx * DC;

  const size_t plane = (size_t)HDIM * WWID;   // 16384 floats
  const float* src = in  + (size_t)b * DDIM * plane;
  float*       dst = out + (size_t)b * DDIM * plane;

  const size_t offb = (size_t)h * WWID + w0;  // this thread's row base
  const bool va = (h > 0);                    // h-1 valid
  const bool vc = (h + 1 < HDIM);             // h+1 valid

  auto loadPlane = [&](int d, float4& ra, float4& rb, float4& rc) {
    if ((unsigned)d < (unsigned)DDIM) {
      const float* p = src + (size_t)d * plane;
      rb = *(const float4*)(p + offb);
      ra = va ? *(const float4*)(p + offb - WWID) : float4{0.f, 0.f, 0.f, 0.f};
      rc = vc ? *(const float4*)(p + offb + WWID) : float4{0.f, 0.f, 0.f, 0.f};
    } else {
      ra = rb = rc = float4{0.f, 0.f, 0.f, 0.f};
    }
  };

  // row partials S (1,2,1) and D (1,0,-1) at the 4 output w positions
  auto rowSD = [&](float4 v, float* S, float* D) {
    const float x1 = (v.x == 255.f) ? 0.f : v.x;   // reference where()
    const float x2 = (v.y == 255.f) ? 0.f : v.y;
    const float x3 = (v.z == 255.f) ? 0.f : v.z;
    const float x4 = (v.w == 255.f) ? 0.f : v.w;
    const float xm = dpp_up1(x4);   // x[w0-1] (0 at w-edge)
    const float xp = dpp_dn1(x1);   // x[w0+4] (0 at w-edge)
    const float x[6] = {xm, x1, x2, x3, x4, xp};
    #pragma unroll
    for (int i = 0; i < 4; ++i) {
      S[i] = fmaf(2.f, x[i + 1], x[i]) + x[i + 2];
      D[i] = x[i] - x[i + 2];
    }
  };

  auto partials = [&](const float4& ra, const float4& rb, const float4& rc, P3& o) {
    float Sa[4], Da[4], Sb[4], Db[4], Sc[4], Dc[4];
    rowSD(ra, Sa, Da);
    rowSD(rb, Sb, Db);
    rowSD(rc, Sc, Dc);
    #pragma unroll
    for (int i = 0; i < 4; ++i) {
      o.ds[i] = Da[i] + Db[i] + Dc[i];
      o.ss[i] = Sa[i] + Sb[i] + Sc[i];
      o.sd[i] = Sa[i] - Sc[i];
    }
  };

  auto emit = [&](int d, const P3& p, const P3& c, const P3& n) {
    float4 o;
    #pragma unroll
    for (int i = 0; i < 4; ++i) {
      const float Gx = fmaf(2.f, c.ds[i], p.ds[i]) + n.ds[i];
      const float Gy = p.ss[i] - n.ss[i];
      const float Gz = p.sd[i] + c.sd[i] + n.sd[i];
      const int cnt = (Gx != 0.f) + (Gy != 0.f) + (Gz != 0.f);
      (&o.x)[i] = (cnt >= 2) ? 1.f : 0.f;
    }
    *(float4*)(dst + (size_t)d * plane + offb) = o;
  };

  float4 A0, B0, C0, A1, B1, C1, A2, B2, C2;   // 3-plane raw ring
  P3 p0, p1, p2;

  // fully unrolled 2-deep pipeline over planes d0-1 .. d0+4 (6 loads, 4 outputs)
  loadPlane(d0 - 1, A0, B0, C0);
  loadPlane(d0,     A1, B1, C1);
  loadPlane(d0 + 1, A2, B2, C2);
  partials(A0, B0, C0, p0);  loadPlane(d0 + 2, A0, B0, C0);
  partials(A1, B1, C1, p1);  loadPlane(d0 + 3, A1, B1, C1);
  partials(A2, B2, C2, p2);  loadPlane(d0 + 4, A2, B2, C2);
  emit(d0,     p0, p1, p2);
  partials(A0, B0, C0, p0);                 // plane d0+2
  emit(d0 + 1, p1, p2, p0);
  partials(A1, B1, C1, p1);                 // plane d0+3
  emit(d0 + 2, p2, p0, p1);
  partials(A2, B2, C2, p2);                 // plane d0+4
  emit(d0 + 3, p0, p1, p2);
}

extern "C" void kernel_launch(void* const* d_in, const int* in_sizes, int n_in,
                              void* d_out, int out_size, void* d_ws, size_t ws_size,
                              hipStream_t stream) {
  const float* data = (const float*)d_in[0];
  // d_in[1] = Sobel weights — fixed by the reference, folded into the kernel.
  float* out = (float*)d_out;
  dim3 grid(8192);                       // 1D; swizzle decoded in-kernel
  dim3 block(WWID, 2);                   // 128 threads = 2 waves
  sobel3d_kernel<<<grid, block, 0, stream>>>(data, out);
}